// Round 6
// baseline (513.385 us; speedup 1.0000x reference)
//
#include <hip/hip_runtime.h>
#include <hip/hip_bf16.h>

// Problem constants (from reference): N=32, T=2048, D_ENC=D_DEC=U=1024
#define NB 32
#define TD 2048
#define DIM 1024
#define NT 16   // K-tiles of 64

typedef _Float16 v8h __attribute__((ext_vector_type(8)));
typedef _Float16 v4h __attribute__((ext_vector_type(4)));
typedef float    v4f __attribute__((ext_vector_type(4)));

__device__ __forceinline__ float ftanh(float x) {
    x = fminf(15.f, fmaxf(-15.f, x));
    float e = __expf(2.f * x);
    return (e - 1.f) / (e + 1.f);
}

__device__ __forceinline__ void gld_lds16(const void* g, void* l) {
    __builtin_amdgcn_global_load_lds(
        (const __attribute__((address_space(1))) unsigned int*)g,
        (__attribute__((address_space(3))) unsigned int*)l, 16, 0, 0);
}

#define SBAR() do { __builtin_amdgcn_sched_barrier(0); \
                    __builtin_amdgcn_s_barrier(); \
                    __builtin_amdgcn_sched_barrier(0); } while (0)

// ---------------- K1 (fused): prep = pq (blocks 0..127) + cvt (blocks 128..33407) ----
__global__ __launch_bounds__(256) void prep_kernel(
        const float* __restrict__ enc, const float* __restrict__ Wk,
        const float* __restrict__ queries, const float* __restrict__ Wq,
        const int* __restrict__ lengths,
        _Float16* __restrict__ ench, _Float16* __restrict__ wkh,
        float* __restrict__ pq) {
    int bid = blockIdx.x;
    if (bid < 128) {
        int lane = threadIdx.x & 63;
        int wv   = threadIdx.x >> 6;
        int u    = bid * 8 + wv * 2;
        const float* w0 = Wq + (size_t)u * DIM;
        const float* w1 = w0 + DIM;
        float4 wq0[4], wq1[4];
#pragma unroll
        for (int j = 0; j < 4; ++j) {
            wq0[j] = *(const float4*)(w0 + j * 256 + lane * 4);
            wq1[j] = *(const float4*)(w1 + j * 256 + lane * 4);
        }
        for (int n = 0; n < NB; ++n) {
            const float* qn = queries + (size_t)n * DIM;
            float s0 = 0.f, s1 = 0.f;
#pragma unroll
            for (int j = 0; j < 4; ++j) {
                float4 qv = *(const float4*)(qn + j * 256 + lane * 4);
                s0 += qv.x * wq0[j].x + qv.y * wq0[j].y + qv.z * wq0[j].z + qv.w * wq0[j].w;
                s1 += qv.x * wq1[j].x + qv.y * wq1[j].y + qv.z * wq1[j].z + qv.w * wq1[j].w;
            }
#pragma unroll
            for (int off = 32; off >= 1; off >>= 1) {
                s0 += __shfl_xor(s0, off);
                s1 += __shfl_xor(s1, off);
            }
            if (lane == 0) {
                pq[(size_t)n * DIM + u]     = s0;
                pq[(size_t)n * DIM + u + 1] = s1;
            }
        }
        return;
    }
    int cb = bid - 128;
    int local = threadIdx.x * 8;
    int rsub  = local >> 10;
    int col   = local & 1023;
    const float* src;
    _Float16* dst;
    size_t row;
    if (cb < 32768) {
        row = (size_t)cb * 2 + rsub;
        int n = (int)(row >> 11), t = (int)(row & 2047);
        if (t >= lengths[n]) return;
        src = enc; dst = ench;
    } else {
        row = (size_t)(cb - 32768) * 2 + rsub;
        src = Wk; dst = wkh;
    }
    const float4* s = (const float4*)(src + row * DIM + col);
    float4 a = s[0], b = s[1];
    v8h h;
    h[0] = (_Float16)a.x; h[1] = (_Float16)a.y; h[2] = (_Float16)a.z; h[3] = (_Float16)a.w;
    h[4] = (_Float16)b.x; h[5] = (_Float16)b.y; h[6] = (_Float16)b.z; h[7] = (_Float16)b.w;
    *(v8h*)(dst + row * DIM + col) = h;
}

// ---------------- K1 (fallback path): standalone pq ----------------
__global__ __launch_bounds__(256) void pq_kernel(const float* __restrict__ q,
                                                 const float* __restrict__ Wq,
                                                 float* __restrict__ pq) {
    int wid  = blockIdx.x * 4 + (threadIdx.x >> 6);
    int lane = threadIdx.x & 63;
    int n = wid >> 10;
    int u = wid & 1023;
    const float4* qr = (const float4*)(q  + (size_t)n * DIM);
    const float4* wr = (const float4*)(Wq + (size_t)u * DIM);
    float s = 0.f;
#pragma unroll
    for (int j = 0; j < 4; ++j) {
        int i = lane + 64 * j;
        float4 a = qr[i], b = wr[i];
        s += a.x * b.x + a.y * b.y + a.z * b.z + a.w * b.w;
    }
#pragma unroll
    for (int off = 32; off >= 1; off >>= 1) s += __shfl_xor(s, off);
    if (lane == 0) pq[(size_t)n * DIM + u] = s;
}

// ---------------- K2 (8-phase 256x256, BK=64): T2+T3+T4+T5 combo ----------------
// 1024 blocks, 512 threads (8 waves: 2M x 4N; per-wave out 128x64, acc[8][4]).
// LDS: 4 half-slots per matrix (A half = 128 rows x 64 f16 = 16 KB) -> 128 KB.
// Proven XOR swizzle: LDS[r][s] = G[r][s^(r&7)] via pre-swizzled global source,
// linear gld_lds dest, swizzled ds_read (rule #21; 0 conflicts measured r1-r5).
// B-frags register-cached per K-tile (read phase 0 only) -> 24 ds_read/wave/iter
// (DS 768 clk/CU/iter ~ MFMA 614 -> not DS-bound).
// Staging schedule (1 half-stage/phase; slot = (2*tile+h)&3; victim-liveness
// verified per placement): ph0 A(t+1,0) / ph1 A(t+1,1) / ph2 B(t+1,1) /
// ph3 B(t+2,0). B(t+1,0) comes from iter t-1 ph3. Iter-end gate: counted
// s_waitcnt vmcnt(2) (B(t+2,0)'s 2 loads stay in flight across the barrier),
// vmcnt(0) only at the tail. Raw s_barrier (no drain) + sched_barrier fences.
// XCD map: xcd=bid&7, j=bid>>3, bn=j&3, g=j>>2, bm=8g|((xcd^g)&7):
// bn-consecutive per bm on one XCD (L2 reuse) + exact stratum balance.
__global__ __launch_bounds__(512, 2) void gemm_tanh_8p(
        const _Float16* __restrict__ ench, const _Float16* __restrict__ wkh,
        const float* __restrict__ pq, const float* __restrict__ v,
        const int* __restrict__ lengths, float* __restrict__ weights) {
    const int bid = blockIdx.x;
    const int xcd = bid & 7;
    const int j   = bid >> 3;                      // [0,128)
    const int g   = j >> 2;                        // [0,32)
    const int bm  = (g << 3) | ((xcd ^ g) & 7);    // [0,256)
    const int bn  = j & 3;
    const int rowBase = bm * 256;
    const int n = rowBase >> 11;
    const int tstart = rowBase & 2047;
    if (lengths[n] <= tstart) return;
    const int bnBase = bn * 256;

    __shared__ _Float16 Asl[4 * 128 * 64];   // 64 KB
    __shared__ _Float16 Bsl[4 * 128 * 64];   // 64 KB

    const int tid  = threadIdx.x;
    const int lane = tid & 63;
    const int wv   = tid >> 6;       // 0..7
    const int wm   = wv >> 2;        // 0..1: A row-half
    const int wn   = wv & 3;         // 0..3: 64-col B slice
    const int q4   = lane >> 4;
    const int l16  = lane & 15;
    const int sr   = lane >> 3;            // staging row 0..7
    const int scs  = (lane & 7) ^ sr;      // pre-swizzled source slot

    auto STAGE_A = [&](int tile, int h) {
        const _Float16* src = ench + (size_t)(rowBase + h * 128 + wv * 16 + sr) * DIM
                              + tile * 64 + scs * 8;
        _Float16* dst = Asl + ((2 * tile + h) & 3) * (128 * 64) + (wv * 16) * 64;
        gld_lds16(src, dst);
        gld_lds16(src + (size_t)8 * DIM, dst + 8 * 64);
    };
    auto STAGE_B = [&](int tile, int h) {
        const _Float16* src = wkh + (size_t)(bnBase + h * 128 + wv * 16 + sr) * DIM
                              + tile * 64 + scs * 8;
        _Float16* dst = Bsl + ((2 * tile + h) & 3) * (128 * 64) + (wv * 16) * 64;
        gld_lds16(src, dst);
        gld_lds16(src + (size_t)8 * DIM, dst + 8 * 64);
    };

    v4f acc[8][4];
    const v4f vz = {0.f, 0.f, 0.f, 0.f};
#pragma unroll
    for (int i = 0; i < 8; ++i)
#pragma unroll
        for (int k = 0; k < 4; ++k) acc[i][k] = vz;

    // prologue: tile0 + B(1,0); gate allows B(1,0)'s 2 loads outstanding.
    STAGE_A(0, 0); STAGE_A(0, 1); STAGE_B(0, 0); STAGE_B(0, 1); STAGE_B(1, 0);
    asm volatile("s_waitcnt vmcnt(2)" ::: "memory");
    SBAR();

    for (int t = 0; t < NT; ++t) {
        v8h breg[2][4];                       // B fragments, live across phases
#pragma unroll
        for (int p = 0; p < 4; ++p) {
            // ds-read A frags for this phase (rows wm*128 + p*32 .. +32)
            v8h a[2][2];
            {
                const _Float16* Ab = Asl + ((2 * t + wm) & 3) * (128 * 64);
#pragma unroll
                for (int ml = 0; ml < 2; ++ml) {
                    int rl = p * 32 + ml * 16 + l16;
                    int sw = rl & 7;
                    a[0][ml] = *(const v8h*)(Ab + rl * 64 + ((q4 ^ sw) * 8));
                    a[1][ml] = *(const v8h*)(Ab + rl * 64 + (((4 + q4) ^ sw) * 8));
                }
            }
            if (p == 0) {                     // B frags once per K-tile
                const _Float16* Bb = Bsl + ((2 * t + (wn >> 1)) & 3) * (128 * 64);
#pragma unroll
                for (int nt = 0; nt < 4; ++nt) {
                    int rl = (wn & 1) * 64 + nt * 16 + l16;
                    int sw = rl & 7;
                    breg[0][nt] = *(const v8h*)(Bb + rl * 64 + ((q4 ^ sw) * 8));
                    breg[1][nt] = *(const v8h*)(Bb + rl * 64 + (((4 + q4) ^ sw) * 8));
                }
            }
            // one half-stage per phase (schedule in header comment)
            if (p == 0)      { if (t + 1 < NT) STAGE_A(t + 1, 0); }
            else if (p == 1) { if (t + 1 < NT) STAGE_A(t + 1, 1); }
            else if (p == 2) { if (t + 1 < NT) STAGE_B(t + 1, 1); }
            else             { if (t + 2 < NT) STAGE_B(t + 2, 0); }

            SBAR();                           // pre-MFMA phase barrier
            __builtin_amdgcn_s_setprio(1);
#pragma unroll
            for (int ml = 0; ml < 2; ++ml)
#pragma unroll
                for (int nt = 0; nt < 4; ++nt) {
                    acc[p * 2 + ml][nt] = __builtin_amdgcn_mfma_f32_16x16x32_f16(
                        a[0][ml], breg[0][nt], acc[p * 2 + ml][nt], 0, 0, 0);
                    acc[p * 2 + ml][nt] = __builtin_amdgcn_mfma_f32_16x16x32_f16(
                        a[1][ml], breg[1][nt], acc[p * 2 + ml][nt], 0, 0, 0);
                }
            __builtin_amdgcn_s_setprio(0);
            if (p < 3) SBAR();                // post-MFMA barrier (ph3 -> gate)
        }
        // iter-end gate: tile t+1 ready; keep B(t+2,0) in flight (counted vmcnt)
        if (t < NT - 1) {
            if (t + 2 < NT) { asm volatile("s_waitcnt vmcnt(2)" ::: "memory"); }
            else            { asm volatile("s_waitcnt vmcnt(0)" ::: "memory"); }
            SBAR();
        }
    }

    // epilogue: tanh + v-weighted reduce over u, atomics (4bn x 4wn = 16/addr)
    float pqv[4], vv[4];
#pragma unroll
    for (int nt = 0; nt < 4; ++nt) {
        int ug = bnBase + wn * 64 + nt * 16 + l16;
        pqv[nt] = pq[(size_t)n * DIM + ug];
        vv[nt]  = v[ug];
    }
#pragma unroll
    for (int mt = 0; mt < 8; ++mt) {
#pragma unroll
        for (int r = 0; r < 4; ++r) {
            float s = 0.f;
#pragma unroll
            for (int nt = 0; nt < 4; ++nt)
                s += ftanh(acc[mt][nt][r] + pqv[nt]) * vv[nt];
            s += __shfl_xor(s, 1);
            s += __shfl_xor(s, 2);
            s += __shfl_xor(s, 4);
            s += __shfl_xor(s, 8);
            if (l16 == 0) {
                int R = rowBase + wm * 128 + mt * 16 + q4 * 4 + r;
                atomicAdd(&weights[R], s);
            }
        }
    }
}

// ---------------- K2 (fallback): inline-convert f32 GEMM ----------------
__global__ __launch_bounds__(256) void gemm_tanh_kernel(
        const float* __restrict__ enc, const float* __restrict__ Wk,
        const float* __restrict__ pq,  const float* __restrict__ v,
        const int* __restrict__ lengths, float* __restrict__ weights) {
    const int bm = blockIdx.x;
    const int bn = blockIdx.y;
    const int rowBase = bm * 128;
    const int n = rowBase >> 11;
    const int tstart = rowBase & 2047;
    if (lengths[n] <= tstart) return;

    __shared__ _Float16 As[128 * 40];
    __shared__ _Float16 Bs[128 * 40];

    const int tid  = threadIdx.x;
    const int lane = tid & 63;
    const int wv   = tid >> 6;
    const int wm   = wv >> 1, wn = wv & 1;
    const int q4   = lane >> 4;
    const int l16  = lane & 15;

    v4f acc[4][4];
    const v4f vz = {0.f, 0.f, 0.f, 0.f};
#pragma unroll
    for (int i = 0; i < 4; ++i)
#pragma unroll
        for (int j = 0; j < 4; ++j) acc[i][j] = vz;

    const int srow = tid >> 3;
    const int skc  = (tid & 7) * 4;

    for (int k0 = 0; k0 < DIM; k0 += 32) {
        __syncthreads();
#pragma unroll
        for (int j = 0; j < 4; ++j) {
            int row = j * 32 + srow;
            float4 av = *(const float4*)(enc + (size_t)(rowBase + row) * DIM + k0 + skc);
            v4h ah;
            ah.x = (_Float16)av.x; ah.y = (_Float16)av.y;
            ah.z = (_Float16)av.z; ah.w = (_Float16)av.w;
            *(v4h*)(&As[row * 40 + skc]) = ah;
            float4 bv = *(const float4*)(Wk + (size_t)(bn * 128 + row) * DIM + k0 + skc);
            v4h bh;
            bh.x = (_Float16)bv.x; bh.y = (_Float16)bv.y;
            bh.z = (_Float16)bv.z; bh.w = (_Float16)bv.w;
            *(v4h*)(&Bs[row * 40 + skc]) = bh;
        }
        __syncthreads();

        v8h afr[4], bfr[4];
#pragma unroll
        for (int mt = 0; mt < 4; ++mt)
            afr[mt] = *(const v8h*)(&As[(wm * 64 + mt * 16 + l16) * 40 + q4 * 8]);
#pragma unroll
        for (int nt = 0; nt < 4; ++nt)
            bfr[nt] = *(const v8h*)(&Bs[(wn * 64 + nt * 16 + l16) * 40 + q4 * 8]);
#pragma unroll
        for (int mt = 0; mt < 4; ++mt)
#pragma unroll
            for (int nt = 0; nt < 4; ++nt)
                acc[mt][nt] = __builtin_amdgcn_mfma_f32_16x16x32_f16(
                    afr[mt], bfr[nt], acc[mt][nt], 0, 0, 0);
    }

    float pqv[4], vv[4];
#pragma unroll
    for (int nt = 0; nt < 4; ++nt) {
        int ug = bn * 128 + wn * 64 + nt * 16 + l16;
        pqv[nt] = pq[(size_t)n * DIM + ug];
        vv[nt]  = v[ug];
    }
#pragma unroll
    for (int mt = 0; mt < 4; ++mt) {
#pragma unroll
        for (int r = 0; r < 4; ++r) {
            float s = 0.f;
#pragma unroll
            for (int nt = 0; nt < 4; ++nt)
                s += ftanh(acc[mt][nt][r] + pqv[nt]) * vv[nt];
            s += __shfl_xor(s, 1);
            s += __shfl_xor(s, 2);
            s += __shfl_xor(s, 4);
            s += __shfl_xor(s, 8);
            if (l16 == 0) {
                int R = rowBase + wm * 64 + mt * 16 + q4 * 4 + r;
                atomicAdd(&weights[R], s);
            }
        }
    }
}

// ---------------- K3: masked softmax per n-row, in place ----------------
__global__ __launch_bounds__(256) void softmax_kernel(float* __restrict__ w,
                                                      const int* __restrict__ lengths) {
    int n = blockIdx.x;
    int len = lengths[n];
    float* row = w + (size_t)n * TD;
    int tid = threadIdx.x;
    float wv[8], ev[8];
    float mx = -INFINITY;
#pragma unroll
    for (int i = 0; i < 8; ++i) {
        int t = tid + i * 256;
        float x = row[t];
        x = (t < len) ? x : -INFINITY;
        wv[i] = x;
        mx = fmaxf(mx, x);
    }
#pragma unroll
    for (int off = 32; off >= 1; off >>= 1) mx = fmaxf(mx, __shfl_xor(mx, off));
    __shared__ float redm[4], reds[4];
    int lane = tid & 63, wvid = tid >> 6;
    if (lane == 0) redm[wvid] = mx;
    __syncthreads();
    mx = fmaxf(fmaxf(redm[0], redm[1]), fmaxf(redm[2], redm[3]));
    float sm = 0.f;
#pragma unroll
    for (int i = 0; i < 8; ++i) { ev[i] = __expf(wv[i] - mx); sm += ev[i]; }
#pragma unroll
    for (int off = 32; off >= 1; off >>= 1) sm += __shfl_xor(sm, off);
    if (lane == 0) reds[wvid] = sm;
    __syncthreads();
    sm = reds[0] + reds[1] + reds[2] + reds[3];
    float inv = 1.f / sm;
#pragma unroll
    for (int i = 0; i < 8; ++i) row[tid + i * 256] = ev[i] * inv;
}

// ---------------- K4 (fast v4): contexts, 64-t chunks ----------------
__global__ __launch_bounds__(256) void ctx_kernel_h4(const float* __restrict__ align,
                                                     const _Float16* __restrict__ ench,
                                                     const int* __restrict__ lengths,
                                                     float* __restrict__ ctx) {
    int n  = blockIdx.y;
    int t0 = blockIdx.x * 64;
    int len = lengths[n];
    if (len <= t0) return;
    int half = threadIdx.x >> 7;
    int col  = (threadIdx.x & 127) * 8;
    float acc[8];
#pragma unroll
    for (int i = 0; i < 8; ++i) acc[i] = 0.f;
    int tend = min(t0 + 64, len);
    const float* arow = align + (size_t)n * TD;
    const _Float16* ebase = ench + (size_t)n * TD * DIM + col;
#pragma unroll 2
    for (int t = t0 + half; t < tend; t += 2) {
        float a = arow[t];
        v8h e = *(const v8h*)(ebase + (size_t)t * DIM);
#pragma unroll
        for (int i = 0; i < 8; ++i) acc[i] += a * (float)e[i];
    }
    __shared__ float cred[DIM];
    if (half == 1) {
#pragma unroll
        for (int i = 0; i < 8; ++i) cred[col + i] = acc[i];
    }
    __syncthreads();
    if (half == 0) {
        float* c = ctx + (size_t)n * DIM + col;
#pragma unroll
        for (int i = 0; i < 8; ++i) atomicAdd(c + i, acc[i] + cred[col + i]);
    }
}

// ---------------- K4 (fallback): f32 enc ----------------
__global__ __launch_bounds__(256) void ctx_kernel(const float* __restrict__ align,
                                                  const float* __restrict__ enc,
                                                  const int* __restrict__ lengths,
                                                  float* __restrict__ ctx) {
    int n  = blockIdx.y;
    int t0 = blockIdx.x * 128;
    if (lengths[n] <= t0) return;
    int e = threadIdx.x * 4;
    float4 acc = make_float4(0.f, 0.f, 0.f, 0.f);
    const float* arow = align + (size_t)n * TD;
    const float* erow = enc + (size_t)n * TD * DIM;
    for (int tt = 0; tt < 128; ++tt) {
        int t = t0 + tt;
        float a = arow[t];
        if (a != 0.f) {
            float4 evv = *(const float4*)(erow + (size_t)t * DIM + e);
            acc.x += a * evv.x; acc.y += a * evv.y;
            acc.z += a * evv.z; acc.w += a * evv.w;
        }
    }
    float* c = ctx + (size_t)n * DIM + e;
    atomicAdd(c + 0, acc.x);
    atomicAdd(c + 1, acc.y);
    atomicAdd(c + 2, acc.z);
    atomicAdd(c + 3, acc.w);
}

extern "C" void kernel_launch(void* const* d_in, const int* in_sizes, int n_in,
                              void* d_out, int out_size, void* d_ws, size_t ws_size,
                              hipStream_t stream) {
    const float* queries = (const float*)d_in[0];   // [32,1,1024]
    const float* enc     = (const float*)d_in[1];   // [32,2048,1024]
    const int*   lengths = (const int*)d_in[2];     // [32]
    const float* v       = (const float*)d_in[3];   // [1024]
    const float* Wq      = (const float*)d_in[4];   // [1024,1024]
    const float* Wk      = (const float*)d_in[5];   // [1024,1024]

    float* out = (float*)d_out;
    float* ctx = out;                // [32,1024]  (also temp home of pq)
    float* alg = out + NB * DIM;     // [32,2048]  (weights -> alignments in place)
    float* pq  = ctx;                // pq fully consumed before ctx memset below
    (void)in_sizes; (void)n_in; (void)out_size;

    const size_t ench_elems = (size_t)NB * TD * DIM;
    const size_t need = (ench_elems + (size_t)DIM * DIM) * sizeof(_Float16);

    hipMemsetAsync(alg, 0, (size_t)NB * TD * sizeof(float), stream);

    if (ws_size >= need) {
        _Float16* ench = (_Float16*)d_ws;
        _Float16* wkh  = ench + ench_elems;
        prep_kernel<<<128 + 32768 + 512, 256, 0, stream>>>(
            enc, Wk, queries, Wq, lengths, ench, wkh, pq);
        gemm_tanh_8p<<<1024, 512, 0, stream>>>(ench, wkh, pq, v, lengths, alg);
        softmax_kernel<<<NB, 256, 0, stream>>>(alg, lengths);
        hipMemsetAsync(ctx, 0, (size_t)NB * DIM * sizeof(float), stream);
        ctx_kernel_h4<<<dim3(32, NB), 256, 0, stream>>>(alg, ench, lengths, ctx);
    } else {
        pq_kernel<<<NB * DIM / 4, 256, 0, stream>>>(queries, Wq, pq);
        dim3 g2(512, 8);
        gemm_tanh_kernel<<<g2, 256, 0, stream>>>(enc, Wk, pq, v, lengths, alg);
        softmax_kernel<<<NB, 256, 0, stream>>>(alg, lengths);
        hipMemsetAsync(ctx, 0, (size_t)NB * DIM * sizeof(float), stream);
        ctx_kernel<<<dim3(16, NB), 256, 0, stream>>>(alg, enc, lengths, ctx);
    }
}